// Round 1
// 90.792 us; speedup vs baseline: 1.0115x; 1.0115x over previous
//
#include <hip/hip_runtime.h>
#include <math.h>

#define F_IN 256
#define NTREES 512
#define DEPTH 6
#define NCOLS (NTREES * DEPTH)   /* 3072 */
#define BATCH 512
#define OUTW (NTREES * 3)        /* 1536 */

typedef __attribute__((ext_vector_type(8))) short bf16x8;
typedef __attribute__((ext_vector_type(4))) float f32x4;
typedef __attribute__((ext_vector_type(8))) unsigned short u16x8;

__device__ __forceinline__ unsigned short f2bf(float x) {
    unsigned u = __float_as_uint(x);
    return (unsigned short)((u + 0x7FFFu + ((u >> 16) & 1u)) >> 16);   // RN-even
}
__device__ __forceinline__ void split2(float x, unsigned short& h, unsigned short& l) {
    h = f2bf(x);
    l = f2bf(x - __uint_as_float((unsigned)h << 16));
}

// ---------------------------------------------------------------------------
// Kernel 1: exact 1.5-entmax. 192 blocks x 256 threads, 16 columns/block.
// NEW: each 16-lane group owns ONE full column (16 elems/lane). The Newton
// butterfly is 4 levels over 16 lanes (xor 1/2/4/8) run simultaneously for
// all 4 groups of a wave -> 8 shuffles/iter instead of 48 (6x less LDS pipe).
// Input conversion blocks removed (k_fused now splits f32 input in-register).
// ---------------------------------------------------------------------------
__global__ __launch_bounds__(256) void k_entmax(const float* __restrict__ att,
                                                unsigned short* __restrict__ cwT_hi,
                                                unsigned short* __restrict__ cwT_lo) {
    const int tid = threadIdx.x;
    const int n0 = blockIdx.x * 16;
    const int lane = tid & 63;
    const int w = tid >> 6;                 // wave 0..3
    const int g = lane >> 4;                // group -> column w*4+g
    const int li = lane & 15;               // lane in group

    __shared__ __align__(16) float s_z[16][260];

    // stage att columns n0..n0+15 into LDS, transposed to [col][f]
    const int cld = tid & 15;
#pragma unroll
    for (int it = 0; it < 16; ++it) {
        int f = (tid >> 4) + it * 16;
        s_z[cld][f] = att[f * NCOLS + n0 + cld];
    }
    __syncthreads();

    const int c = w * 4 + g;
    float4 z[4];
#pragma unroll
    for (int j = 0; j < 4; ++j) {
        float4 v = *(const float4*)&s_z[c][li * 16 + 4 * j];
        z[j] = make_float4(v.x * 0.5f, v.y * 0.5f, v.z * 0.5f, v.w * 0.5f);
    }
    // group max (16 elems local, then 4-level butterfly within 16 lanes)
    float m = fmaxf(fmaxf(fmaxf(z[0].x, z[0].y), fmaxf(z[0].z, z[0].w)),
                    fmaxf(fmaxf(z[1].x, z[1].y), fmaxf(z[1].z, z[1].w)));
    m = fmaxf(m, fmaxf(fmaxf(fmaxf(z[2].x, z[2].y), fmaxf(z[2].z, z[2].w)),
                       fmaxf(fmaxf(z[3].x, z[3].y), fmaxf(z[3].z, z[3].w))));
#pragma unroll
    for (int off = 8; off >= 1; off >>= 1) m = fmaxf(m, __shfl_xor(m, off));
#pragma unroll
    for (int j = 0; j < 4; ++j) {
        z[j].x -= m; z[j].y -= m; z[j].z -= m; z[j].w -= m;
    }

    float tau = -1.0f;                      // f(zmax-1) >= 0 guaranteed
    for (int iter = 0; iter < 14; ++iter) {
        float s1p[4], s2p[4];
#pragma unroll
        for (int j = 0; j < 4; ++j) {
            float d0 = fmaxf(z[j].x - tau, 0.f);
            float d1 = fmaxf(z[j].y - tau, 0.f);
            float d2 = fmaxf(z[j].z - tau, 0.f);
            float d3 = fmaxf(z[j].w - tau, 0.f);
            s1p[j] = (d0 + d1) + (d2 + d3);
            s2p[j] = fmaf(d0, d0, fmaf(d1, d1, fmaf(d2, d2, d3 * d3)));
        }
        float s1 = (s1p[0] + s1p[1]) + (s1p[2] + s1p[3]);
        float s2 = (s2p[0] + s2p[1]) + (s2p[2] + s2p[3]);
#pragma unroll
        for (int off = 8; off >= 1; off >>= 1) {
            s1 += __shfl_xor(s1, off);
            s2 += __shfl_xor(s2, off);
        }
        tau += (s2 - 1.f) / (2.f * s1);     // Newton
        if (__all(fabsf(s2 - 1.f) < 4e-6f)) break;   // wave-uniform
    }

#pragma unroll
    for (int j = 0; j < 4; ++j) {
        float4 pv;
        float v0 = fmaxf(z[j].x - tau, 0.f);
        float v1 = fmaxf(z[j].y - tau, 0.f);
        float v2 = fmaxf(z[j].z - tau, 0.f);
        float v3 = fmaxf(z[j].w - tau, 0.f);
        pv.x = v0 * v0; pv.y = v1 * v1; pv.z = v2 * v2; pv.w = v3 * v3;
        *(float4*)&s_z[c][li * 16 + 4 * j] = pv;
    }
    __syncthreads();

    // bf16 hi/lo plane writeout, [n][f] row-major
    const int nl = tid >> 4;
    const int f0 = (tid & 15) * 16;
#pragma unroll
    for (int jj = 0; jj < 2; ++jj) {
        u16x8 hv, lv;
#pragma unroll
        for (int e = 0; e < 8; ++e) {
            unsigned short h, l;
            split2(s_z[nl][f0 + jj * 8 + e], h, l);
            hv[e] = h; lv[e] = l;
        }
        *(u16x8*)&cwT_hi[(n0 + nl) * F_IN + f0 + jj * 8] = hv;
        *(u16x8*)&cwT_lo[(n0 + nl) * F_IN + f0 + jj * 8] = lv;
    }
}

// ---------------------------------------------------------------------------
// Kernel 2 (fused GEMM + tree): 512 threads (8 waves -> 2 waves/SIMD),
// block = 8 trees (48 n-cols) x 128 batch. Phase 1: wave tile 48n x 16b via
// split-bf16 MFMA; B operand is f32 input split hi/lo IN-REGISTER (same bytes
// as bf16 planes, no conversion kernel / global round-trip). Phase 2: tree
// index is wave-uniform -> readfirstlane forces resp/thr/ltemp onto the
// SCALAR pipe (s_load, K$); dot is v_fmac with SGPR operand; zero LDS traffic
// for the response table. Grid = 64 x 4 = 256 blocks = 1/CU.
// ---------------------------------------------------------------------------
__global__ __launch_bounds__(512) void k_fused(const unsigned short* __restrict__ Ah,
                                               const unsigned short* __restrict__ Al,
                                               const float* __restrict__ inp,
                                               const float* __restrict__ thr,
                                               const float* __restrict__ ltemp,
                                               const float* __restrict__ resp,
                                               float* __restrict__ out) {
    const int tb  = blockIdx.x;            // tree block
    const int b0  = blockIdx.y * 128;
    const int t0g = tb * 8;
    const int n0g = tb * 48;               // fv-column base = t0g*6
    const int tid = threadIdx.x;
    const int wave = tid >> 6, lane = tid & 63;
    const int quad = lane >> 4, lr = lane & 15;

    __shared__ float sFV[48][132];         // fv tile [n][b], pad 132
    __shared__ float sO[128][25];          // output staging

    // ---- Phase 1: MFMA GEMM, wave tile = 48n x 16b ----
    const int bw = b0 + wave * 16;
    const unsigned short* pah = Ah + (n0g + lr) * F_IN + quad * 8;
    const unsigned short* pal = Al + (n0g + lr) * F_IN + quad * 8;
    const float* pbf = inp + (bw + lr) * F_IN + quad * 8;

    f32x4 acc[3];
#pragma unroll
    for (int i = 0; i < 3; ++i) acc[i] = (f32x4){0.f, 0.f, 0.f, 0.f};

#pragma unroll
    for (int k0 = 0; k0 < F_IN; k0 += 32) {
        bf16x8 ah[3], al[3], bh, bl;
#pragma unroll
        for (int i = 0; i < 3; ++i) {
            ah[i] = *(const bf16x8*)(pah + i * 16 * F_IN + k0);
            al[i] = *(const bf16x8*)(pal + i * 16 * F_IN + k0);
        }
        float4 v0 = *(const float4*)(pbf + k0);
        float4 v1 = *(const float4*)(pbf + k0 + 4);
        float fb[8] = {v0.x, v0.y, v0.z, v0.w, v1.x, v1.y, v1.z, v1.w};
#pragma unroll
        for (int e = 0; e < 8; ++e) {
            unsigned short hh, ll;
            split2(fb[e], hh, ll);
            bh[e] = (short)hh; bl[e] = (short)ll;
        }
#pragma unroll
        for (int i = 0; i < 3; ++i) {
            acc[i] = __builtin_amdgcn_mfma_f32_16x16x32_bf16(ah[i], bh, acc[i], 0, 0, 0);
            acc[i] = __builtin_amdgcn_mfma_f32_16x16x32_bf16(ah[i], bl, acc[i], 0, 0, 0);
            acc[i] = __builtin_amdgcn_mfma_f32_16x16x32_bf16(al[i], bh, acc[i], 0, 0, 0);
        }
    }
    // C/D layout: col = lane&15 (b), row = quad*4 + r (n)  [m89-verified]
#pragma unroll
    for (int i = 0; i < 3; ++i)
#pragma unroll
        for (int r = 0; r < 4; ++r)
            sFV[16 * i + quad * 4 + r][wave * 16 + lr] = acc[i][r];
    __syncthreads();

    // ---- Phase 2: 8 trees x 128 b = 1024 pairs, 2 per thread ----
#pragma unroll
    for (int p = 0; p < 2; ++p) {
        const int pi = p * 512 + tid;
        const int tl = pi >> 7;            // local tree 0..7, wave-uniform
        const int b  = pi & 127;
        const int tls = __builtin_amdgcn_readfirstlane(tl);   // force scalar
        const float* rp = resp + (size_t)(t0g + tls) * 192;   // s_load path
        const float* tp = thr   + (t0g + tls) * 6;
        const float* lp = ltemp + (t0g + tls) * 6;

        float bpos[6], bneg[6];
#pragma unroll
        for (int d = 0; d < 6; ++d) {
            float fvv = sFV[tls * 6 + d][b];
            float tlv = (fvv - tp[d]) * __expf(-lp[d]);
            float hp = 0.5f * tlv + 0.5f;
            float hn = 0.5f - 0.5f * tlv;
            bpos[d] = fminf(fmaxf(hp, -0.5f), 1.5f);   // bit d == 0
            bneg[d] = fminf(fmaxf(hn, -0.5f), 1.5f);   // bit d == 1
        }
        float pr[64];
        pr[0] = 1.f;
#pragma unroll
        for (int d = 0; d < 6; ++d) {
            int half = 1 << d;
#pragma unroll 32
            for (int i = half - 1; i >= 0; --i) {
                float v = pr[i];
                pr[i + half] = v * bneg[d];
                pr[i]        = v * bpos[d];
            }
        }
        float a0 = 0.f, a1 = 0.f, a2 = 0.f;
#pragma unroll
        for (int cc = 0; cc < 64; ++cc) {
            a0 = fmaf(pr[cc], rp[cc], a0);          // v_fmac with SGPR src
            a1 = fmaf(pr[cc], rp[64 + cc], a1);
            a2 = fmaf(pr[cc], rp[128 + cc], a2);
        }
        sO[b][tl * 3 + 0] = a0;
        sO[b][tl * 3 + 1] = a1;
        sO[b][tl * 3 + 2] = a2;
    }
    __syncthreads();
    for (int i = tid; i < 128 * 24; i += 512) {
        int row = i / 24, col = i % 24;
        out[(b0 + row) * OUTW + t0g * 3 + col] = sO[row][col];
    }
}

extern "C" void kernel_launch(void* const* d_in, const int* in_sizes, int n_in,
                              void* d_out, int out_size, void* d_ws, size_t ws_size,
                              hipStream_t stream) {
    const float* input = (const float*)d_in[0];   // [512, 256]
    const float* att   = (const float*)d_in[1];   // [256, 3072]
    const float* thr   = (const float*)d_in[2];   // [512, 6]
    const float* ltemp = (const float*)d_in[3];   // [512, 6]
    const float* resp  = (const float*)d_in[4];   // [512, 3, 64]
    float* out = (float*)d_out;                   // [512, 1536]

    unsigned short* cwT_hi = (unsigned short*)d_ws;          // [3072][256] bf16
    unsigned short* cwT_lo = cwT_hi + NCOLS * F_IN;

    hipLaunchKernelGGL(k_entmax, dim3(NCOLS / 16), dim3(256), 0, stream,
                       att, cwT_hi, cwT_lo);
    hipLaunchKernelGGL(k_fused, dim3(NTREES / 8, BATCH / 128), dim3(512), 0, stream,
                       cwT_hi, cwT_lo, input, thr, ltemp, resp, out);
}

// Round 2
// 86.412 us; speedup vs baseline: 1.0627x; 1.0507x over previous
//
#include <hip/hip_runtime.h>
#include <math.h>

#define F_IN 256
#define NTREES 512
#define DEPTH 6
#define NCOLS (NTREES * DEPTH)   /* 3072 */
#define BATCH 512
#define OUTW (NTREES * 3)        /* 1536 */

typedef __attribute__((ext_vector_type(8))) short bf16x8;
typedef __attribute__((ext_vector_type(4))) float f32x4;

__device__ __forceinline__ unsigned short f2bf(float x) {
    unsigned u = __float_as_uint(x);
    return (unsigned short)((u + 0x7FFFu + ((u >> 16) & 1u)) >> 16);   // RN-even
}
__device__ __forceinline__ void split2(float x, unsigned short& h, unsigned short& l) {
    h = f2bf(x);
    l = f2bf(x - __uint_as_float((unsigned)h << 16));
}

// ---------------------------------------------------------------------------
// Single fully-fused kernel: entmax + split-bf16 MFMA GEMM + soft tree + out.
// Grid 64 (tree-blocks) x 4 (batch-blocks), 512 threads (8 waves, 2/SIMD).
// Each block recomputes entmax for its 48 att columns in-LDS (per-column
// independent; 4x duplication across batch-blocks is ~1.5us of parallel VALU
// and removes the second kernel + the 6 MiB workspace round-trip entirely).
// ZERO d_ws usage -> tests whether the 41us/iter 256MiB workspace poison fill
// is conditional on workspace use.
// LDS: s.z[48][260] f32 (49.9KB) unioned with phase-2 fv/o buffers.
// ---------------------------------------------------------------------------
__global__ __launch_bounds__(512) void k_all(const float* __restrict__ att,
                                             const float* __restrict__ inp,
                                             const float* __restrict__ thr,
                                             const float* __restrict__ ltemp,
                                             const float* __restrict__ resp,
                                             float* __restrict__ out) {
    const int tb  = blockIdx.x;            // tree block 0..63
    const int b0  = blockIdx.y * 128;
    const int t0g = tb * 8;
    const int n0g = tb * 48;
    const int tid = threadIdx.x;
    const int wave = tid >> 6, lane = tid & 63;
    const int quad = lane >> 4, lr = lane & 15;

    __shared__ union {
        float z[48][260];                            // entmax working tile [col][f]
        struct { float fv[48][132]; float o[128][25]; } p2;
    } s;

    // ---- stage att (48 cols x 256 rows) transposed into s.z[col][f] ----
    {
        const int c4 = tid & 15;                     // float4-column 0..11 valid
        const int fr = tid >> 4;                     // row 0..31
        if (c4 < 12) {
#pragma unroll
            for (int it = 0; it < 8; ++it) {
                int f = fr + it * 32;
                float4 v = *(const float4*)&att[f * NCOLS + n0g + 4 * c4];
                s.z[4 * c4 + 0][f] = v.x;
                s.z[4 * c4 + 1][f] = v.y;
                s.z[4 * c4 + 2][f] = v.z;
                s.z[4 * c4 + 3][f] = v.w;
            }
        }
    }
    __syncthreads();

    // ---- entmax: 48 groups of 8 lanes (waves 0..5), 32 elems/lane ----
    if (wave < 6) {
        const int c  = tid >> 3;                     // column 0..47
        const int li = tid & 7;
        float4 z[8];
#pragma unroll
        for (int j = 0; j < 8; ++j) {
            float4 v = *(const float4*)&s.z[c][li * 32 + 4 * j];
            z[j] = make_float4(v.x * 0.5f, v.y * 0.5f, v.z * 0.5f, v.w * 0.5f);
        }
        float m = -1e30f;
#pragma unroll
        for (int j = 0; j < 8; ++j)
            m = fmaxf(m, fmaxf(fmaxf(z[j].x, z[j].y), fmaxf(z[j].z, z[j].w)));
#pragma unroll
        for (int off = 4; off >= 1; off >>= 1) m = fmaxf(m, __shfl_xor(m, off));
#pragma unroll
        for (int j = 0; j < 8; ++j) {
            z[j].x -= m; z[j].y -= m; z[j].z -= m; z[j].w -= m;
        }

        float tau = -1.0f;                           // f(zmax-1) >= 0 guaranteed
        for (int iter = 0; iter < 14; ++iter) {
            float s1 = 0.f, s2 = 0.f;
#pragma unroll
            for (int j = 0; j < 8; ++j) {
                float d0 = fmaxf(z[j].x - tau, 0.f);
                float d1 = fmaxf(z[j].y - tau, 0.f);
                float d2 = fmaxf(z[j].z - tau, 0.f);
                float d3 = fmaxf(z[j].w - tau, 0.f);
                s1 += (d0 + d1) + (d2 + d3);
                s2 = fmaf(d0, d0, fmaf(d1, d1, fmaf(d2, d2, fmaf(d3, d3, s2))));
            }
#pragma unroll
            for (int off = 4; off >= 1; off >>= 1) {
                s1 += __shfl_xor(s1, off);
                s2 += __shfl_xor(s2, off);
            }
            tau += (s2 - 1.f) / (2.f * s1);          // Newton
            if (__all(fabsf(s2 - 1.f) < 4e-6f)) break;   // wave-uniform
        }
#pragma unroll
        for (int j = 0; j < 8; ++j) {
            float v0 = fmaxf(z[j].x - tau, 0.f);
            float v1 = fmaxf(z[j].y - tau, 0.f);
            float v2 = fmaxf(z[j].z - tau, 0.f);
            float v3 = fmaxf(z[j].w - tau, 0.f);
            float4 pv;
            pv.x = v0 * v0; pv.y = v1 * v1; pv.z = v2 * v2; pv.w = v3 * v3;
            *(float4*)&s.z[c][li * 32 + 4 * j] = pv;
        }
    }
    __syncthreads();

    // ---- Phase 1: MFMA GEMM, wave tile = 48n x 16b.
    // A read as f32 from s.z, hi/lo split in-register (numerics identical to
    // the old bf16-plane path). B split in-register from f32 input.
    const int bw = b0 + wave * 16;
    const float* pbf = inp + (bw + lr) * F_IN + quad * 8;

    f32x4 acc[3];
#pragma unroll
    for (int i = 0; i < 3; ++i) acc[i] = (f32x4){0.f, 0.f, 0.f, 0.f};

#pragma unroll
    for (int k0 = 0; k0 < F_IN; k0 += 32) {
        bf16x8 ah[3], al[3], bh, bl;
#pragma unroll
        for (int i = 0; i < 3; ++i) {
            float4 a0 = *(const float4*)&s.z[16 * i + lr][quad * 8 + k0];
            float4 a1 = *(const float4*)&s.z[16 * i + lr][quad * 8 + k0 + 4];
            float fa[8] = {a0.x, a0.y, a0.z, a0.w, a1.x, a1.y, a1.z, a1.w};
#pragma unroll
            for (int e = 0; e < 8; ++e) {
                unsigned short hh, ll;
                split2(fa[e], hh, ll);
                ah[i][e] = (short)hh; al[i][e] = (short)ll;
            }
        }
        float4 v0 = *(const float4*)(pbf + k0);
        float4 v1 = *(const float4*)(pbf + k0 + 4);
        float fb[8] = {v0.x, v0.y, v0.z, v0.w, v1.x, v1.y, v1.z, v1.w};
#pragma unroll
        for (int e = 0; e < 8; ++e) {
            unsigned short hh, ll;
            split2(fb[e], hh, ll);
            bh[e] = (short)hh; bl[e] = (short)ll;
        }
#pragma unroll
        for (int i = 0; i < 3; ++i) {
            acc[i] = __builtin_amdgcn_mfma_f32_16x16x32_bf16(ah[i], bh, acc[i], 0, 0, 0);
            acc[i] = __builtin_amdgcn_mfma_f32_16x16x32_bf16(ah[i], bl, acc[i], 0, 0, 0);
            acc[i] = __builtin_amdgcn_mfma_f32_16x16x32_bf16(al[i], bh, acc[i], 0, 0, 0);
        }
    }
    __syncthreads();                        // all s.z reads done -> safe to alias

    // C/D layout: col = lane&15 (b), row = quad*4 + r (n)  [m89-verified]
#pragma unroll
    for (int i = 0; i < 3; ++i)
#pragma unroll
        for (int r = 0; r < 4; ++r)
            s.p2.fv[16 * i + quad * 4 + r][wave * 16 + lr] = acc[i][r];
    __syncthreads();

    // ---- Phase 2: 8 trees x 128 b = 1024 pairs, 2 per thread ----
#pragma unroll
    for (int p = 0; p < 2; ++p) {
        const int pi = p * 512 + tid;
        const int tl = pi >> 7;            // local tree 0..7, wave-uniform
        const int b  = pi & 127;
        const int tls = __builtin_amdgcn_readfirstlane(tl);   // force scalar path
        const float* rp = resp  + (size_t)(t0g + tls) * 192;  // s_load / K$
        const float* tp = thr   + (t0g + tls) * 6;
        const float* lp = ltemp + (t0g + tls) * 6;

        float bpos[6], bneg[6];
#pragma unroll
        for (int d = 0; d < 6; ++d) {
            float fvv = s.p2.fv[tls * 6 + d][b];
            float tlv = (fvv - tp[d]) * __expf(-lp[d]);
            float hp = 0.5f * tlv + 0.5f;
            float hn = 0.5f - 0.5f * tlv;
            bpos[d] = fminf(fmaxf(hp, -0.5f), 1.5f);   // bit d == 0
            bneg[d] = fminf(fmaxf(hn, -0.5f), 1.5f);   // bit d == 1
        }
        float pr[64];
        pr[0] = 1.f;
#pragma unroll
        for (int d = 0; d < 6; ++d) {
            int half = 1 << d;
#pragma unroll 32
            for (int i = half - 1; i >= 0; --i) {
                float v = pr[i];
                pr[i + half] = v * bneg[d];
                pr[i]        = v * bpos[d];
            }
        }
        float a0 = 0.f, a1 = 0.f, a2 = 0.f;
#pragma unroll
        for (int cc = 0; cc < 64; ++cc) {
            a0 = fmaf(pr[cc], rp[cc], a0);             // v_fmac with SGPR src
            a1 = fmaf(pr[cc], rp[64 + cc], a1);
            a2 = fmaf(pr[cc], rp[128 + cc], a2);
        }
        s.p2.o[b][tl * 3 + 0] = a0;
        s.p2.o[b][tl * 3 + 1] = a1;
        s.p2.o[b][tl * 3 + 2] = a2;
    }
    __syncthreads();
    for (int i = tid; i < 128 * 24; i += 512) {
        int row = i / 24, col = i % 24;
        out[(b0 + row) * OUTW + t0g * 3 + col] = s.p2.o[row][col];
    }
}

extern "C" void kernel_launch(void* const* d_in, const int* in_sizes, int n_in,
                              void* d_out, int out_size, void* d_ws, size_t ws_size,
                              hipStream_t stream) {
    const float* input = (const float*)d_in[0];   // [512, 256]
    const float* att   = (const float*)d_in[1];   // [256, 3072]
    const float* thr   = (const float*)d_in[2];   // [512, 6]
    const float* ltemp = (const float*)d_in[3];   // [512, 6]
    const float* resp  = (const float*)d_in[4];   // [512, 3, 64]
    float* out = (float*)d_out;                   // [512, 1536]
    (void)d_ws; (void)ws_size;                    // workspace intentionally unused

    hipLaunchKernelGGL(k_all, dim3(NTREES / 8, BATCH / 128), dim3(512), 0, stream,
                       att, input, thr, ltemp, resp, out);
}

// Round 3
// 84.244 us; speedup vs baseline: 1.0901x; 1.0257x over previous
//
#include <hip/hip_runtime.h>
#include <math.h>

#define F_IN 256
#define NTREES 512
#define DEPTH 6
#define NCOLS (NTREES * DEPTH)   /* 3072 */
#define BATCH 512
#define OUTW (NTREES * 3)        /* 1536 */

typedef __attribute__((ext_vector_type(8))) short bf16x8;
typedef __attribute__((ext_vector_type(4))) float f32x4;
typedef __attribute__((ext_vector_type(8))) unsigned short u16x8;

__device__ __forceinline__ unsigned short f2bf(float x) {
    unsigned u = __float_as_uint(x);
    return (unsigned short)((u + 0x7FFFu + ((u >> 16) & 1u)) >> 16);   // RN-even
}
__device__ __forceinline__ void split2(float x, unsigned short& h, unsigned short& l) {
    h = f2bf(x);
    l = f2bf(x - __uint_as_float((unsigned)h << 16));
}

// ---------------------------------------------------------------------------
// Single fully-fused kernel: entmax + split-bf16 MFMA GEMM + soft tree + out.
// Grid 64 (tree-blocks) x 4 (batch-blocks), 512 threads (8 waves, 2/SIMD).
// ROUND 3 CHANGE: entmax epilogue emits bf16 hi/lo PLANES into LDS (split2
// done ONCE per element) instead of f32; the GEMM reads A-fragments directly
// as bf16x8 via ds_read_b128. Removes ~1150 redundant VALU ops/lane (each of
// the 8 waves was re-splitting the same 48x256 A-tile every k-step). Output
// bit-identical: same f32 values through the same split2.
// LDS: union{ f32 z[48][260] | planes h/l[48][264] | phase2 fv+o } = 49.5 KB.
// Barrier discipline: stage -> B1 -> reg-load (reads z) -> B2 -> newton +
// plane writes (alias z) -> B3 -> GEMM (reads planes) -> B4 -> fv (aliases
// planes) -> B5 -> tree -> B6 -> out.
// ---------------------------------------------------------------------------
__global__ __launch_bounds__(512) void k_all(const float* __restrict__ att,
                                             const float* __restrict__ inp,
                                             const float* __restrict__ thr,
                                             const float* __restrict__ ltemp,
                                             const float* __restrict__ resp,
                                             float* __restrict__ out) {
    const int tb  = blockIdx.x;            // tree block 0..63
    const int b0  = blockIdx.y * 128;
    const int t0g = tb * 8;
    const int n0g = tb * 48;
    const int tid = threadIdx.x;
    const int wave = tid >> 6, lane = tid & 63;
    const int quad = lane >> 4, lr = lane & 15;

    __shared__ union {
        float z[48][260];                                    // entmax f32 stage
        struct { unsigned short h[48][264];
                 unsigned short l[48][264]; } pl;            // bf16 hi/lo planes
        struct { float fv[48][132]; float o[128][25]; } p2;  // tree phase
    } s;

    // ---- stage att (48 cols x 256 rows) transposed into s.z[col][f] ----
    {
        const int c4 = tid & 15;                     // float4-column 0..11 valid
        const int fr = tid >> 4;                     // row 0..31
        if (c4 < 12) {
#pragma unroll
            for (int it = 0; it < 8; ++it) {
                int f = fr + it * 32;
                float4 v = *(const float4*)&att[f * NCOLS + n0g + 4 * c4];
                s.z[4 * c4 + 0][f] = v.x;
                s.z[4 * c4 + 1][f] = v.y;
                s.z[4 * c4 + 2][f] = v.z;
                s.z[4 * c4 + 3][f] = v.w;
            }
        }
    }
    __syncthreads();                                 // B1

    // ---- entmax: 48 groups of 8 lanes (waves 0..5), 32 elems/lane ----
    const bool act = (wave < 6);
    const int c  = tid >> 3;                         // column 0..47 (if act)
    const int li = tid & 7;
    float4 z[8];
    if (act) {
#pragma unroll
        for (int j = 0; j < 8; ++j) {
            float4 v = *(const float4*)&s.z[c][li * 32 + 4 * j];
            z[j] = make_float4(v.x * 0.5f, v.y * 0.5f, v.z * 0.5f, v.w * 0.5f);
        }
    }
    __syncthreads();                                 // B2: all z reads done

    if (act) {
        float m = -1e30f;
#pragma unroll
        for (int j = 0; j < 8; ++j)
            m = fmaxf(m, fmaxf(fmaxf(z[j].x, z[j].y), fmaxf(z[j].z, z[j].w)));
#pragma unroll
        for (int off = 4; off >= 1; off >>= 1) m = fmaxf(m, __shfl_xor(m, off));
#pragma unroll
        for (int j = 0; j < 8; ++j) {
            z[j].x -= m; z[j].y -= m; z[j].z -= m; z[j].w -= m;
        }

        float tau = -1.0f;                           // f(zmax-1) >= 0 guaranteed
        for (int iter = 0; iter < 14; ++iter) {
            float s1 = 0.f, s2 = 0.f;
#pragma unroll
            for (int j = 0; j < 8; ++j) {
                float d0 = fmaxf(z[j].x - tau, 0.f);
                float d1 = fmaxf(z[j].y - tau, 0.f);
                float d2 = fmaxf(z[j].z - tau, 0.f);
                float d3 = fmaxf(z[j].w - tau, 0.f);
                s1 += (d0 + d1) + (d2 + d3);
                s2 = fmaf(d0, d0, fmaf(d1, d1, fmaf(d2, d2, fmaf(d3, d3, s2))));
            }
#pragma unroll
            for (int off = 4; off >= 1; off >>= 1) {
                s1 += __shfl_xor(s1, off);
                s2 += __shfl_xor(s2, off);
            }
            tau += (s2 - 1.f) / (2.f * s1);          // Newton
            if (__all(fabsf(s2 - 1.f) < 4e-6f)) break;   // wave-uniform
        }

        // epilogue: p = clip(z - tau)^2, split to bf16 hi/lo ONCE, store planes
#pragma unroll
        for (int jj = 0; jj < 4; ++jj) {
            float pv[8];
#pragma unroll
            for (int hh = 0; hh < 2; ++hh) {
                float4 zz = z[2 * jj + hh];
                float v0 = fmaxf(zz.x - tau, 0.f);
                float v1 = fmaxf(zz.y - tau, 0.f);
                float v2 = fmaxf(zz.z - tau, 0.f);
                float v3 = fmaxf(zz.w - tau, 0.f);
                pv[4 * hh + 0] = v0 * v0; pv[4 * hh + 1] = v1 * v1;
                pv[4 * hh + 2] = v2 * v2; pv[4 * hh + 3] = v3 * v3;
            }
            u16x8 hv, lv;
#pragma unroll
            for (int e = 0; e < 8; ++e) {
                unsigned short h, l;
                split2(pv[e], h, l);
                hv[e] = h; lv[e] = l;
            }
            *(u16x8*)&s.pl.h[c][li * 32 + 8 * jj] = hv;
            *(u16x8*)&s.pl.l[c][li * 32 + 8 * jj] = lv;
        }
    }
    __syncthreads();                                 // B3: planes ready

    // ---- Phase 1: MFMA GEMM, wave tile = 48n x 16b.
    // A read directly as bf16 planes from LDS; B split in-register from f32.
    const int bw = b0 + wave * 16;
    const float* pbf = inp + (bw + lr) * F_IN + quad * 8;

    f32x4 acc[3];
#pragma unroll
    for (int i = 0; i < 3; ++i) acc[i] = (f32x4){0.f, 0.f, 0.f, 0.f};

#pragma unroll
    for (int k0 = 0; k0 < F_IN; k0 += 32) {
        bf16x8 ah[3], al[3], bh, bl;
#pragma unroll
        for (int i = 0; i < 3; ++i) {
            ah[i] = *(const bf16x8*)&s.pl.h[16 * i + lr][quad * 8 + k0];
            al[i] = *(const bf16x8*)&s.pl.l[16 * i + lr][quad * 8 + k0];
        }
        float4 v0 = *(const float4*)(pbf + k0);
        float4 v1 = *(const float4*)(pbf + k0 + 4);
        float fb[8] = {v0.x, v0.y, v0.z, v0.w, v1.x, v1.y, v1.z, v1.w};
#pragma unroll
        for (int e = 0; e < 8; ++e) {
            unsigned short hh, ll;
            split2(fb[e], hh, ll);
            bh[e] = (short)hh; bl[e] = (short)ll;
        }
#pragma unroll
        for (int i = 0; i < 3; ++i) {
            acc[i] = __builtin_amdgcn_mfma_f32_16x16x32_bf16(ah[i], bh, acc[i], 0, 0, 0);
            acc[i] = __builtin_amdgcn_mfma_f32_16x16x32_bf16(ah[i], bl, acc[i], 0, 0, 0);
            acc[i] = __builtin_amdgcn_mfma_f32_16x16x32_bf16(al[i], bh, acc[i], 0, 0, 0);
        }
    }
    __syncthreads();                        // B4: plane reads done -> alias ok

    // C/D layout: col = lane&15 (b), row = quad*4 + r (n)  [m89-verified]
#pragma unroll
    for (int i = 0; i < 3; ++i)
#pragma unroll
        for (int r = 0; r < 4; ++r)
            s.p2.fv[16 * i + quad * 4 + r][wave * 16 + lr] = acc[i][r];
    __syncthreads();                                 // B5

    // ---- Phase 2: 8 trees x 128 b = 1024 pairs, 2 per thread ----
#pragma unroll
    for (int p = 0; p < 2; ++p) {
        const int pi = p * 512 + tid;
        const int tl = pi >> 7;            // local tree 0..7, wave-uniform
        const int b  = pi & 127;
        const int tls = __builtin_amdgcn_readfirstlane(tl);   // force scalar path
        const float* rp = resp  + (size_t)(t0g + tls) * 192;  // s_load / K$
        const float* tp = thr   + (t0g + tls) * 6;
        const float* lp = ltemp + (t0g + tls) * 6;

        float bpos[6], bneg[6];
#pragma unroll
        for (int d = 0; d < 6; ++d) {
            float fvv = s.p2.fv[tls * 6 + d][b];
            float tlv = (fvv - tp[d]) * __expf(-lp[d]);
            float hp = 0.5f * tlv + 0.5f;
            float hn = 0.5f - 0.5f * tlv;
            bpos[d] = fminf(fmaxf(hp, -0.5f), 1.5f);   // bit d == 0
            bneg[d] = fminf(fmaxf(hn, -0.5f), 1.5f);   // bit d == 1
        }
        float pr[64];
        pr[0] = 1.f;
#pragma unroll
        for (int d = 0; d < 6; ++d) {
            int half = 1 << d;
#pragma unroll 32
            for (int i = half - 1; i >= 0; --i) {
                float v = pr[i];
                pr[i + half] = v * bneg[d];
                pr[i]        = v * bpos[d];
            }
        }
        float a0 = 0.f, a1 = 0.f, a2 = 0.f;
#pragma unroll
        for (int cc = 0; cc < 64; ++cc) {
            a0 = fmaf(pr[cc], rp[cc], a0);             // v_fmac with SGPR src
            a1 = fmaf(pr[cc], rp[64 + cc], a1);
            a2 = fmaf(pr[cc], rp[128 + cc], a2);
        }
        s.p2.o[b][tl * 3 + 0] = a0;
        s.p2.o[b][tl * 3 + 1] = a1;
        s.p2.o[b][tl * 3 + 2] = a2;
    }
    __syncthreads();                                 // B6
    for (int i = tid; i < 128 * 24; i += 512) {
        int row = i / 24, col = i % 24;
        out[(b0 + row) * OUTW + t0g * 3 + col] = s.p2.o[row][col];
    }
}

extern "C" void kernel_launch(void* const* d_in, const int* in_sizes, int n_in,
                              void* d_out, int out_size, void* d_ws, size_t ws_size,
                              hipStream_t stream) {
    const float* input = (const float*)d_in[0];   // [512, 256]
    const float* att   = (const float*)d_in[1];   // [256, 3072]
    const float* thr   = (const float*)d_in[2];   // [512, 6]
    const float* ltemp = (const float*)d_in[3];   // [512, 6]
    const float* resp  = (const float*)d_in[4];   // [512, 3, 64]
    float* out = (float*)d_out;                   // [512, 1536]
    (void)d_ws; (void)ws_size;                    // workspace intentionally unused

    hipLaunchKernelGGL(k_all, dim3(NTREES / 8, BATCH / 128), dim3(512), 0, stream,
                       att, input, thr, ltemp, resp, out);
}